// Round 7
// baseline (235.737 us; speedup 1.0000x reference)
//
#include <hip/hip_runtime.h>
#include <hip/hip_bf16.h>

#define D 128

typedef _Float16 f16;
typedef f16  f16x8 __attribute__((ext_vector_type(8)));
typedef f16  f16x2 __attribute__((ext_vector_type(2)));
typedef float f32x4 __attribute__((ext_vector_type(4)));

// ---------------------------------------------------------------- count edges
__global__ __launch_bounds__(256) void count_edges(const int* __restrict__ col,
                                                   int* __restrict__ cnt, int E) {
    int t = blockIdx.x * blockDim.x + threadIdx.x;
    if (t < E) atomicAdd(&cnt[col[t]], 1);
}

// ------------------------------------------- scan phase A: block partial sums
__global__ __launch_bounds__(256) void scan_partial(const int* __restrict__ cnt,
                                                    float* __restrict__ dis,
                                                    int* __restrict__ bsum, int N) {
    int i = blockIdx.x * 256 + threadIdx.x;
    int v = 0;
    if (i < N) {
        v = cnt[i] + 1;
        dis[i] = rsqrtf((float)v);
    }
    int s = v;
#pragma unroll
    for (int d = 1; d < 64; d <<= 1) s += __shfl_xor(s, d);
    __shared__ int ws[4];
    int lane = threadIdx.x & 63, w = threadIdx.x >> 6;
    if (lane == 0) ws[w] = s;
    __syncthreads();
    if (threadIdx.x == 0) bsum[blockIdx.x] = ws[0] + ws[1] + ws[2] + ws[3];
}

// ----------------- scan phase B+C fused: final offsets (off and cursor)
// Every block redundantly scans the <=256 block sums in LDS (~1us), saving
// the separate 1-block kernel launch.
__global__ __launch_bounds__(256) void scan_final(const int* __restrict__ cnt,
                                                  const int* __restrict__ bsum,
                                                  int* __restrict__ off,
                                                  int* __restrict__ cursor,
                                                  int N, int Etot, int nb) {
    __shared__ int ws[4];
    __shared__ int pre[256];
    const int t = threadIdx.x, lane = t & 63, w = t >> 6;

    // --- scan of block sums (exclusive), all blocks recompute
    {
        int v = (t < nb) ? bsum[t] : 0;
        int sc = v;
#pragma unroll
        for (int d = 1; d < 64; d <<= 1) {
            int y = __shfl_up(sc, d);
            if (lane >= d) sc += y;
        }
        if (lane == 63) ws[w] = sc;
        __syncthreads();
        int add = 0;
        for (int j = 0; j < w; ++j) add += ws[j];
        pre[t] = add + sc - v;
        __syncthreads();   // pre visible; ws reads done before reuse below
    }
    const int base = pre[blockIdx.x];

    // --- per-element scan within this block
    int i = blockIdx.x * 256 + t;
    int v = (i < N) ? cnt[i] + 1 : 0;
    int sc = v;
#pragma unroll
    for (int d = 1; d < 64; d <<= 1) {
        int y = __shfl_up(sc, d);
        if (lane >= d) sc += y;
    }
    if (lane == 63) ws[w] = sc;
    __syncthreads();
    int add = 0;
    for (int j = 0; j < w; ++j) add += ws[j];
    int ex = base + add + sc - v;
    if (i < N) {
        off[i] = ex;
        cursor[i] = ex;
    }
    if (blockIdx.x == 0 && t == 0) off[N] = Etot;
}

// ----------------------------------------------------------------- CSR fill
// Writes ONLY eidx (one scattered line per edge); the edge norm is
// recomputed on the fly in spmm_row from the L2-resident dis table.
__global__ __launch_bounds__(256) void fill_edges(const int* __restrict__ row,
                                                  const int* __restrict__ col,
                                                  int* __restrict__ cursor,
                                                  int* __restrict__ eidx,
                                                  int E, int N) {
    int t = blockIdx.x * blockDim.x + threadIdx.x;
    if (t < E) {
        int r = row[t], c = col[t];
        int p = atomicAdd(&cursor[c], 1);
        eidx[p] = r;
    } else if (t < E + N) {
        int i = t - E;
        int p = atomicAdd(&cursor[i], 1);
        eidx[p] = i;
    }
}

// ---------------------------------------------- W transpose + fp16 (one-time)
__global__ __launch_bounds__(1024) void transpose_w(const float* __restrict__ W1,
                                                    const float* __restrict__ W2,
                                                    f16* __restrict__ W1t,
                                                    f16* __restrict__ W2t) {
    const float* W = blockIdx.x ? W2 : W1;
    f16* Wt = blockIdx.x ? W2t : W1t;
    __shared__ float Wl[128 * 130];
    const int t = threadIdx.x;
    for (int i = t; i < 16384; i += 1024)
        Wl[(i >> 7) * 130 + (i & 127)] = W[i];
    __syncthreads();
    for (int i = t; i < 16384; i += 1024) {
        int n = i >> 7, k = i & 127;
        Wt[i] = (f16)Wl[k * 130 + n];
    }
}

// ----------------------------------------------------------- MFMA GEMM (fp16)
// Hh[N,128] (fp16) = X[N,128] (f32) @ W, using Wt (fp16, [n][k]).
// 256 thr = 4 waves; wave w owns rows rbase+16w..+15, all 128 cols.
__global__ __launch_bounds__(256) void gemm_mfma(const float* __restrict__ X,
                                                 const f16* __restrict__ Wt,
                                                 f16* __restrict__ Hh, int N) {
    const int w = threadIdx.x >> 6, l = threadIdx.x & 63;
    const int trow = blockIdx.x * 64 + w * 16;       // tile row base
    const int arow = trow + (l & 15);                // A-frag row for this lane
    const int kg = l >> 4;                           // k-group 0..3

    f16x8 a[4];
    const float* xr = X + (size_t)arow * D;
#pragma unroll
    for (int kt = 0; kt < 4; ++kt) {
        float4 p0, p1;
        if (arow < N) {
            p0 = *(const float4*)&xr[kt * 32 + kg * 8];
            p1 = *(const float4*)&xr[kt * 32 + kg * 8 + 4];
        } else {
            p0.x = p0.y = p0.z = p0.w = 0.f;
            p1 = p0;
        }
        a[kt][0] = (f16)p0.x; a[kt][1] = (f16)p0.y;
        a[kt][2] = (f16)p0.z; a[kt][3] = (f16)p0.w;
        a[kt][4] = (f16)p1.x; a[kt][5] = (f16)p1.y;
        a[kt][6] = (f16)p1.z; a[kt][7] = (f16)p1.w;
    }

    const int drow = trow + kg * 4;                  // D rows drow..drow+3
#pragma unroll
    for (int nt = 0; nt < 8; ++nt) {
        f32x4 acc = {0.f, 0.f, 0.f, 0.f};
        const f16* wrow = Wt + (size_t)(nt * 16 + (l & 15)) * D;
#pragma unroll
        for (int kt = 0; kt < 4; ++kt) {
            f16x8 b = *(const f16x8*)&wrow[kt * 32 + kg * 8];
            acc = __builtin_amdgcn_mfma_f32_16x16x32_f16(a[kt], b, acc, 0, 0, 0);
        }
        const int dcol = nt * 16 + (l & 15);
#pragma unroll
        for (int r = 0; r < 4; ++r) {
            int orow = drow + r;
            if (orow < N) Hh[(size_t)orow * D + dcol] = (f16)acc[r];
        }
    }
}

// --------------------------------------------------------- SpMM + bias + ReLU
// Gathers fp16 H rows (256 B per edge per wave), norm computed on the fly:
// dis[c] loop-invariant, dis[eidx[k]] a wave-uniform broadcast load (L2-hot).
__global__ __launch_bounds__(256) void spmm_row(const f16* __restrict__ Hh,
                                                const int* __restrict__ off,
                                                const int* __restrict__ eidx,
                                                const float* __restrict__ dis,
                                                const float* __restrict__ bias,
                                                float* __restrict__ O, int N) {
    const int c = blockIdx.x * 4 + (threadIdx.x >> 6);
    if (c >= N) return;
    const int lane = threadIdx.x & 63;
    const int d0 = lane * 2;
    const int s = off[c], e = off[c + 1];
    const float dc = dis[c];
    float ax = bias[d0], ay = bias[d0 + 1];
    int k = s;
    for (; k + 8 <= e; k += 8) {
        int r[8];
#pragma unroll
        for (int j = 0; j < 8; ++j) r[j] = eidx[k + j];
        f16x2 h[8];
        float dr[8];
#pragma unroll
        for (int j = 0; j < 8; ++j) {
            h[j] = *(const f16x2*)&Hh[(size_t)r[j] * D + d0];
            dr[j] = dis[r[j]];
        }
#pragma unroll
        for (int j = 0; j < 8; ++j) {
            float w = dr[j] * dc;
            ax += (float)h[j][0] * w;
            ay += (float)h[j][1] * w;
        }
    }
    for (; k < e; ++k) {
        int r = eidx[k];
        f16x2 h = *(const f16x2*)&Hh[(size_t)r * D + d0];
        float w = dis[r] * dc;
        ax += (float)h[0] * w;
        ay += (float)h[1] * w;
    }
    float2 o;
    o.x = fmaxf(ax, 0.f);
    o.y = fmaxf(ay, 0.f);
    *(float2*)&O[(size_t)c * D + d0] = o;
}

// ----------------------------------------------------------------- head GEMV
__global__ __launch_bounds__(256) void head_kernel(const float* __restrict__ H,
                                                   const float* __restrict__ Wh,
                                                   const float* __restrict__ bh,
                                                   float* __restrict__ out, int N) {
    int gt = blockIdx.x * blockDim.x + threadIdx.x;
    int wid = gt >> 6;
    int lane = gt & 63;
    if (wid >= N) return;
    const float* hrow = H + (size_t)wid * D;
    float x0 = hrow[lane], x1 = hrow[lane + 64];
    float a0 = x0 * Wh[lane * 3 + 0] + x1 * Wh[(lane + 64) * 3 + 0];
    float a1 = x0 * Wh[lane * 3 + 1] + x1 * Wh[(lane + 64) * 3 + 1];
    float a2 = x0 * Wh[lane * 3 + 2] + x1 * Wh[(lane + 64) * 3 + 2];
#pragma unroll
    for (int s = 32; s > 0; s >>= 1) {
        a0 += __shfl_down(a0, s);
        a1 += __shfl_down(a1, s);
        a2 += __shfl_down(a2, s);
    }
    if (lane == 0) {
        out[wid * 3 + 0] = a0 + bh[0];
        out[wid * 3 + 1] = a1 + bh[1];
        out[wid * 3 + 2] = a2 + bh[2];
    }
}

// ---------------------------------------------------------------------------
extern "C" void kernel_launch(void* const* d_in, const int* in_sizes, int n_in,
                              void* d_out, int out_size, void* d_ws, size_t ws_size,
                              hipStream_t stream) {
    const float* x  = (const float*)d_in[0];
    const int*   ei = (const int*)d_in[1];
    const float* W1 = (const float*)d_in[2];
    const float* b1 = (const float*)d_in[3];
    const float* W2 = (const float*)d_in[4];
    const float* b2 = (const float*)d_in[5];
    const float* Wh = (const float*)d_in[6];
    const float* bh = (const float*)d_in[7];
    float* out = (float*)d_out;

    const int N = in_sizes[0] / D;       // 50000
    const int E = in_sizes[1] / 2;       // 800000
    const int Etot = E + N;
    const int* row = ei;
    const int* col = ei + E;

    // -------- workspace layout
    char* ws = (char*)d_ws;
    size_t o = 0;
    auto alloc = [&](size_t bytes) -> char* {
        char* p = ws + o;
        o = (o + bytes + 255) & ~(size_t)255;
        return p;
    };
    const int nb = (N + 255) / 256;
    int*   cnt    = (int*)  alloc((size_t)N * 4);
    int*   off    = (int*)  alloc((size_t)(N + 1) * 4);
    int*   cursor = (int*)  alloc((size_t)N * 4);
    float* dis    = (float*)alloc((size_t)N * 4);
    int*   bsum   = (int*)  alloc((size_t)nb * 4);
    int*   eidx   = (int*)  alloc((size_t)Etot * 4);
    f16*   W1t    = (f16*)  alloc((size_t)128 * 128 * 2);
    f16*   W2t    = (f16*)  alloc((size_t)128 * 128 * 2);
    f16*   Hh     = (f16*)  alloc((size_t)N * D * 2);   // gather matrix (fp16)
    float* B      = (float*)alloc((size_t)N * D * 4);   // conv output (f32)
    (void)ws_size;

    hipMemsetAsync(cnt, 0, (size_t)N * 4, stream);
    count_edges<<<(E + 255) / 256, 256, 0, stream>>>(col, cnt, E);
    scan_partial<<<nb, 256, 0, stream>>>(cnt, dis, bsum, N);
    scan_final<<<nb, 256, 0, stream>>>(cnt, bsum, off, cursor, N, Etot, nb);
    fill_edges<<<(Etot + 255) / 256, 256, 0, stream>>>(row, col, cursor, eidx, E, N);
    transpose_w<<<2, 1024, 0, stream>>>(W1, W2, W1t, W2t);

    const int gblocks = (N + 63) / 64;   // 64 rows per block (4 waves x 16)
    const int sblocks = (N + 3) / 4;     // 4 targets per block
    gemm_mfma<<<gblocks, 256, 0, stream>>>(x, W1t, Hh, N);
    spmm_row<<<sblocks, 256, 0, stream>>>(Hh, off, eidx, dis, b1, B, N);
    gemm_mfma<<<gblocks, 256, 0, stream>>>(B, W2t, Hh, N);
    spmm_row<<<sblocks, 256, 0, stream>>>(Hh, off, eidx, dis, b2, B, N);
    head_kernel<<<((size_t)N * 64 + 255) / 256, 256, 0, stream>>>(B, Wh, bh, out, N);
}

// Round 8
// 217.066 us; speedup vs baseline: 1.0860x; 1.0860x over previous
//
#include <hip/hip_runtime.h>
#include <hip/hip_bf16.h>

#define D 128
#define NBSH 7          // 128 targets per bucket
#define CHUNK 8192      // edges per partition block
#define BCAP 8192       // LDS CSR-region capacity (ints) per bucket

typedef _Float16 f16;
typedef f16  f16x8 __attribute__((ext_vector_type(8)));
typedef f16  f16x2 __attribute__((ext_vector_type(2)));
typedef float f32x4 __attribute__((ext_vector_type(4)));

// ---------------------------------------------------------------- count edges
__global__ __launch_bounds__(256) void count_edges(const int* __restrict__ col,
                                                   int* __restrict__ cnt, int E) {
    int t = blockIdx.x * blockDim.x + threadIdx.x;
    if (t < E) atomicAdd(&cnt[col[t]], 1);
}

// ------------------------------------------- scan phase A: block partial sums
__global__ __launch_bounds__(256) void scan_partial(const int* __restrict__ cnt,
                                                    float* __restrict__ dis,
                                                    int* __restrict__ bsum, int N) {
    int i = blockIdx.x * 256 + threadIdx.x;
    int v = 0;
    if (i < N) {
        v = cnt[i] + 1;
        dis[i] = rsqrtf((float)v);
    }
    int s = v;
#pragma unroll
    for (int d = 1; d < 64; d <<= 1) s += __shfl_xor(s, d);
    __shared__ int ws[4];
    int lane = threadIdx.x & 63, w = threadIdx.x >> 6;
    if (lane == 0) ws[w] = s;
    __syncthreads();
    if (threadIdx.x == 0) bsum[blockIdx.x] = ws[0] + ws[1] + ws[2] + ws[3];
}

// ----------------- scan phase B+C fused: off[] + per-bucket staging bases
// bcur[b] = off[128b] - 128b  (# real edges before bucket b, since off
// counts deg=cnt+1 per target -> subtracting the self-loop slots).
__global__ __launch_bounds__(256) void scan_final(const int* __restrict__ cnt,
                                                  const int* __restrict__ bsum,
                                                  int* __restrict__ off,
                                                  int* __restrict__ bcur,
                                                  int N, int Etot, int nb) {
    __shared__ int ws[4];
    __shared__ int pre[256];
    const int t = threadIdx.x, lane = t & 63, w = t >> 6;

    {   // exclusive scan of block sums, recomputed by every block
        int v = (t < nb) ? bsum[t] : 0;
        int sc = v;
#pragma unroll
        for (int d = 1; d < 64; d <<= 1) {
            int y = __shfl_up(sc, d);
            if (lane >= d) sc += y;
        }
        if (lane == 63) ws[w] = sc;
        __syncthreads();
        int add = 0;
        for (int j = 0; j < w; ++j) add += ws[j];
        pre[t] = add + sc - v;
        __syncthreads();
    }
    const int base = pre[blockIdx.x];

    int i = blockIdx.x * 256 + t;
    int v = (i < N) ? cnt[i] + 1 : 0;
    int sc = v;
#pragma unroll
    for (int d = 1; d < 64; d <<= 1) {
        int y = __shfl_up(sc, d);
        if (lane >= d) sc += y;
    }
    if (lane == 63) ws[w] = sc;
    __syncthreads();
    int add = base;
    for (int j = 0; j < w; ++j) add += ws[j];
    int ex = add + sc - v;
    if (i < N) {
        off[i] = ex;
        if ((i & 127) == 0) bcur[i >> NBSH] = ex - i;   // staging base
    }
    if (blockIdx.x == 0 && t == 0) off[N] = Etot;
}

// ------------------------------------- pass 1: bucket partition (dense writes)
// Block sorts CHUNK edges by bucket in LDS, then flushes contiguous runs.
__global__ __launch_bounds__(256) void partition_edges(const int* __restrict__ row,
                                                       const int* __restrict__ col,
                                                       int* __restrict__ bcur,
                                                       int2* __restrict__ bstage,
                                                       int E, int NB) {
    __shared__ int2 sorted[CHUNK];     // 64 KB
    __shared__ int hist[512];
    __shared__ int scanb[512];
    __shared__ int lcur[512];
    __shared__ int gdel[512];
    const int t = threadIdx.x;
    const int base = blockIdx.x * CHUNK;
    const int cnt = min(CHUNK, E - base);

    for (int i = t; i < 512; i += 256) hist[i] = 0;
    __syncthreads();
    for (int i = t; i < cnt; i += 256)
        atomicAdd(&hist[col[base + i] >> NBSH], 1);
    __syncthreads();
    // inclusive Hillis-Steele scan of 512 entries (2 per thread)
    for (int i = t; i < 512; i += 256) scanb[i] = hist[i];
    __syncthreads();
    for (int s = 1; s < 512; s <<= 1) {
        int i0 = t, i1 = t + 256;
        int v0 = scanb[i0] + ((i0 >= s) ? scanb[i0 - s] : 0);
        int v1 = scanb[i1] + ((i1 >= s) ? scanb[i1 - s] : 0);
        __syncthreads();
        scanb[i0] = v0; scanb[i1] = v1;
        __syncthreads();
    }
    for (int i = t; i < 512; i += 256) lcur[i] = scanb[i] - hist[i];
    __syncthreads();
    // local bucket sort into LDS
    for (int i = t; i < cnt; i += 256) {
        int r = row[base + i], c = col[base + i];
        int pos = atomicAdd(&lcur[c >> NBSH], 1);
        int2 p; p.x = r; p.y = c;
        sorted[pos] = p;
    }
    __syncthreads();
    // one global atomic per nonempty bucket
    for (int b = t; b < NB; b += 256) {
        int k = hist[b];
        if (k > 0) {
            int g = atomicAdd(&bcur[b], k);
            gdel[b] = g - (scanb[b] - k);   // global pos minus local base
        }
    }
    __syncthreads();
    // flush: contiguous runs per bucket
    for (int i = t; i < cnt; i += 256) {
        int2 p = sorted[i];
        bstage[gdel[p.y >> NBSH] + i] = p;
    }
}

// ------------------------------------- pass 2: per-bucket LDS scatter + stream
__global__ __launch_bounds__(256) void bucket_fill(const int2* __restrict__ bstage,
                                                   const int* __restrict__ off,
                                                   int* __restrict__ eidx, int N) {
    __shared__ int leidx[BCAP];        // 32 KB
    __shared__ int lcur[128];
    const int b = blockIdx.x;
    const int tb = b << NBSH;
    const int ntgt = min(128, N - tb);
    const int gbase = off[tb];
    const int gend = off[tb + ntgt];
    const int total = gend - gbase;
    const int sbase = gbase - tb;      // staging base for this bucket
    const int nedge = total - ntgt;    // real edges
    const int t = threadIdx.x;

    if (total <= BCAP) {
        if (t < ntgt) {                // self-loops first
            int g = off[tb + t] - gbase;
            leidx[g] = tb + t;
            lcur[t] = g + 1;
        }
        __syncthreads();
        for (int i = t; i < nedge; i += 256) {
            int2 p = bstage[sbase + i];
            int pos = atomicAdd(&lcur[p.y - tb], 1);
            leidx[pos] = p.x;
        }
        __syncthreads();
        for (int i = t; i < total; i += 256)   // coalesced full-line stream
            eidx[gbase + i] = leidx[i];
    } else {                            // impossible-for-random fallback
        if (t < ntgt) {
            int g = off[tb + t];
            eidx[g] = tb + t;
            lcur[t] = g + 1;
        }
        __syncthreads();
        for (int i = t; i < nedge; i += 256) {
            int2 p = bstage[sbase + i];
            int pos = atomicAdd(&lcur[p.y - tb], 1);
            eidx[pos] = p.x;
        }
    }
}

// ---------------------------------------------- W transpose + fp16 (one-time)
__global__ __launch_bounds__(1024) void transpose_w(const float* __restrict__ W1,
                                                    const float* __restrict__ W2,
                                                    f16* __restrict__ W1t,
                                                    f16* __restrict__ W2t) {
    const float* W = blockIdx.x ? W2 : W1;
    f16* Wt = blockIdx.x ? W2t : W1t;
    __shared__ float Wl[128 * 130];
    const int t = threadIdx.x;
    for (int i = t; i < 16384; i += 1024)
        Wl[(i >> 7) * 130 + (i & 127)] = W[i];
    __syncthreads();
    for (int i = t; i < 16384; i += 1024) {
        int n = i >> 7, k = i & 127;
        Wt[i] = (f16)Wl[k * 130 + n];
    }
}

// ----------------------------------------------------------- MFMA GEMM (fp16)
__global__ __launch_bounds__(256) void gemm_mfma(const float* __restrict__ X,
                                                 const f16* __restrict__ Wt,
                                                 f16* __restrict__ Hh, int N) {
    const int w = threadIdx.x >> 6, l = threadIdx.x & 63;
    const int trow = blockIdx.x * 64 + w * 16;
    const int arow = trow + (l & 15);
    const int kg = l >> 4;

    f16x8 a[4];
    const float* xr = X + (size_t)arow * D;
#pragma unroll
    for (int kt = 0; kt < 4; ++kt) {
        float4 p0, p1;
        if (arow < N) {
            p0 = *(const float4*)&xr[kt * 32 + kg * 8];
            p1 = *(const float4*)&xr[kt * 32 + kg * 8 + 4];
        } else {
            p0.x = p0.y = p0.z = p0.w = 0.f;
            p1 = p0;
        }
        a[kt][0] = (f16)p0.x; a[kt][1] = (f16)p0.y;
        a[kt][2] = (f16)p0.z; a[kt][3] = (f16)p0.w;
        a[kt][4] = (f16)p1.x; a[kt][5] = (f16)p1.y;
        a[kt][6] = (f16)p1.z; a[kt][7] = (f16)p1.w;
    }

    const int drow = trow + kg * 4;
#pragma unroll
    for (int nt = 0; nt < 8; ++nt) {
        f32x4 acc = {0.f, 0.f, 0.f, 0.f};
        const f16* wrow = Wt + (size_t)(nt * 16 + (l & 15)) * D;
#pragma unroll
        for (int kt = 0; kt < 4; ++kt) {
            f16x8 b = *(const f16x8*)&wrow[kt * 32 + kg * 8];
            acc = __builtin_amdgcn_mfma_f32_16x16x32_f16(a[kt], b, acc, 0, 0, 0);
        }
        const int dcol = nt * 16 + (l & 15);
#pragma unroll
        for (int r = 0; r < 4; ++r) {
            int orow = drow + r;
            if (orow < N) Hh[(size_t)orow * D + dcol] = (f16)acc[r];
        }
    }
}

// --------------------------------------------------------- SpMM + bias + ReLU
__global__ __launch_bounds__(256) void spmm_row(const f16* __restrict__ Hh,
                                                const int* __restrict__ off,
                                                const int* __restrict__ eidx,
                                                const float* __restrict__ dis,
                                                const float* __restrict__ bias,
                                                float* __restrict__ O, int N) {
    const int c = blockIdx.x * 4 + (threadIdx.x >> 6);
    if (c >= N) return;
    const int lane = threadIdx.x & 63;
    const int d0 = lane * 2;
    const int s = off[c], e = off[c + 1];
    const float dc = dis[c];
    float ax = bias[d0], ay = bias[d0 + 1];
    int k = s;
    for (; k + 8 <= e; k += 8) {
        int r[8];
#pragma unroll
        for (int j = 0; j < 8; ++j) r[j] = eidx[k + j];
        f16x2 h[8];
        float dr[8];
#pragma unroll
        for (int j = 0; j < 8; ++j) {
            h[j] = *(const f16x2*)&Hh[(size_t)r[j] * D + d0];
            dr[j] = dis[r[j]];
        }
#pragma unroll
        for (int j = 0; j < 8; ++j) {
            float w = dr[j] * dc;
            ax += (float)h[j][0] * w;
            ay += (float)h[j][1] * w;
        }
    }
    for (; k < e; ++k) {
        int r = eidx[k];
        f16x2 h = *(const f16x2*)&Hh[(size_t)r * D + d0];
        float w = dis[r] * dc;
        ax += (float)h[0] * w;
        ay += (float)h[1] * w;
    }
    float2 o;
    o.x = fmaxf(ax, 0.f);
    o.y = fmaxf(ay, 0.f);
    *(float2*)&O[(size_t)c * D + d0] = o;
}

// ----------------------------------------------------------------- head GEMV
__global__ __launch_bounds__(256) void head_kernel(const float* __restrict__ H,
                                                   const float* __restrict__ Wh,
                                                   const float* __restrict__ bh,
                                                   float* __restrict__ out, int N) {
    int gt = blockIdx.x * blockDim.x + threadIdx.x;
    int wid = gt >> 6;
    int lane = gt & 63;
    if (wid >= N) return;
    const float* hrow = H + (size_t)wid * D;
    float x0 = hrow[lane], x1 = hrow[lane + 64];
    float a0 = x0 * Wh[lane * 3 + 0] + x1 * Wh[(lane + 64) * 3 + 0];
    float a1 = x0 * Wh[lane * 3 + 1] + x1 * Wh[(lane + 64) * 3 + 1];
    float a2 = x0 * Wh[lane * 3 + 2] + x1 * Wh[(lane + 64) * 3 + 2];
#pragma unroll
    for (int s = 32; s > 0; s >>= 1) {
        a0 += __shfl_down(a0, s);
        a1 += __shfl_down(a1, s);
        a2 += __shfl_down(a2, s);
    }
    if (lane == 0) {
        out[wid * 3 + 0] = a0 + bh[0];
        out[wid * 3 + 1] = a1 + bh[1];
        out[wid * 3 + 2] = a2 + bh[2];
    }
}

// ---------------------------------------------------------------------------
extern "C" void kernel_launch(void* const* d_in, const int* in_sizes, int n_in,
                              void* d_out, int out_size, void* d_ws, size_t ws_size,
                              hipStream_t stream) {
    const float* x  = (const float*)d_in[0];
    const int*   ei = (const int*)d_in[1];
    const float* W1 = (const float*)d_in[2];
    const float* b1 = (const float*)d_in[3];
    const float* W2 = (const float*)d_in[4];
    const float* b2 = (const float*)d_in[5];
    const float* Wh = (const float*)d_in[6];
    const float* bh = (const float*)d_in[7];
    float* out = (float*)d_out;

    const int N = in_sizes[0] / D;       // 50000
    const int E = in_sizes[1] / 2;       // 800000
    const int Etot = E + N;
    const int* row = ei;
    const int* col = ei + E;
    const int NB = (N + 127) >> NBSH;    // 391 buckets

    // -------- workspace layout
    char* ws = (char*)d_ws;
    size_t o = 0;
    auto alloc = [&](size_t bytes) -> char* {
        char* p = ws + o;
        o = (o + bytes + 255) & ~(size_t)255;
        return p;
    };
    const int nb = (N + 255) / 256;
    int*   cnt    = (int*)  alloc((size_t)N * 4);
    int*   off    = (int*)  alloc((size_t)(N + 1) * 4);
    float* dis    = (float*)alloc((size_t)N * 4);
    int*   bsum   = (int*)  alloc((size_t)nb * 4);
    int*   bcur   = (int*)  alloc((size_t)NB * 4);
    int2*  bstage = (int2*) alloc((size_t)E * 8);
    int*   eidx   = (int*)  alloc((size_t)Etot * 4);
    f16*   W1t    = (f16*)  alloc((size_t)128 * 128 * 2);
    f16*   W2t    = (f16*)  alloc((size_t)128 * 128 * 2);
    f16*   Hh     = (f16*)  alloc((size_t)N * D * 2);   // gather matrix (fp16)
    float* B      = (float*)alloc((size_t)N * D * 4);   // conv output (f32)
    (void)ws_size;

    hipMemsetAsync(cnt, 0, (size_t)N * 4, stream);
    count_edges<<<(E + 255) / 256, 256, 0, stream>>>(col, cnt, E);
    scan_partial<<<nb, 256, 0, stream>>>(cnt, dis, bsum, N);
    scan_final<<<nb, 256, 0, stream>>>(cnt, bsum, off, bcur, N, Etot, nb);
    partition_edges<<<(E + CHUNK - 1) / CHUNK, 256, 0, stream>>>(row, col, bcur,
                                                                 bstage, E, NB);
    bucket_fill<<<NB, 256, 0, stream>>>(bstage, off, eidx, N);
    transpose_w<<<2, 1024, 0, stream>>>(W1, W2, W1t, W2t);

    const int gblocks = (N + 63) / 64;
    const int sblocks = (N + 3) / 4;
    gemm_mfma<<<gblocks, 256, 0, stream>>>(x, W1t, Hh, N);
    spmm_row<<<sblocks, 256, 0, stream>>>(Hh, off, eidx, dis, b1, B, N);
    gemm_mfma<<<gblocks, 256, 0, stream>>>(B, W2t, Hh, N);
    spmm_row<<<sblocks, 256, 0, stream>>>(Hh, off, eidx, dis, b2, B, N);
    head_kernel<<<((size_t)N * 64 + 255) / 256, 256, 0, stream>>>(B, Wh, bh, out, N);
}

// Round 9
// 173.495 us; speedup vs baseline: 1.3588x; 1.2511x over previous
//
#include <hip/hip_runtime.h>
#include <hip/hip_bf16.h>
#include <type_traits>

#define D 128
#define NBSH 7          // 128 targets per bucket
#define CHUNK 8192      // edges per partition block
#define CAP 4096        // staging capacity per bucket (mean 2048, sigma~45)

typedef _Float16 f16;
typedef f16  f16x8 __attribute__((ext_vector_type(8)));
typedef f16  f16x2 __attribute__((ext_vector_type(2)));
typedef float f32x4 __attribute__((ext_vector_type(4)));

// ------------------------------------- pass 1: bucket partition (dense writes)
// Block sorts CHUNK edges by bucket in LDS, then flushes contiguous runs into
// fixed-capacity per-bucket staging regions (bcur zeroed beforehand).
__global__ __launch_bounds__(256) void partition_edges(const int* __restrict__ row,
                                                       const int* __restrict__ col,
                                                       int* __restrict__ bcur,
                                                       int2* __restrict__ bstage,
                                                       int E, int NB) {
    __shared__ int2 sorted[CHUNK];     // 64 KB
    __shared__ int hist[512];
    __shared__ int scanb[512];
    __shared__ int lcur[512];
    __shared__ int gdel[512];
    const int t = threadIdx.x;
    const int base = blockIdx.x * CHUNK;
    const int cnt = min(CHUNK, E - base);

    for (int i = t; i < 512; i += 256) hist[i] = 0;
    __syncthreads();
    for (int i = t; i < cnt; i += 256)
        atomicAdd(&hist[col[base + i] >> NBSH], 1);
    __syncthreads();
    for (int i = t; i < 512; i += 256) scanb[i] = hist[i];
    __syncthreads();
    for (int s = 1; s < 512; s <<= 1) {
        int i0 = t, i1 = t + 256;
        int v0 = scanb[i0] + ((i0 >= s) ? scanb[i0 - s] : 0);
        int v1 = scanb[i1] + ((i1 >= s) ? scanb[i1 - s] : 0);
        __syncthreads();
        scanb[i0] = v0; scanb[i1] = v1;
        __syncthreads();
    }
    for (int i = t; i < 512; i += 256) lcur[i] = scanb[i] - hist[i];
    __syncthreads();
    for (int i = t; i < cnt; i += 256) {
        int r = row[base + i], c = col[base + i];
        int pos = atomicAdd(&lcur[c >> NBSH], 1);
        int2 p; p.x = r; p.y = c;
        sorted[pos] = p;
    }
    __syncthreads();
    for (int b = t; b < NB; b += 256) {
        int k = hist[b];
        if (k > 0) {
            int g = atomicAdd(&bcur[b], k);
            gdel[b] = b * CAP + g - (scanb[b] - k);
        }
    }
    __syncthreads();
    for (int i = t; i < cnt; i += 256) {
        int2 p = sorted[i];
        bstage[gdel[p.y >> NBSH] + i] = p;
    }
}

// --------------- pass 2: per-bucket CSR build (off, dis, eidx) + LDS scatter
// Each block redundantly scans the NB bucket counts for its global base, then
// histograms its own staged edges to build the local CSR entirely in LDS.
__global__ __launch_bounds__(256) void bucket_fill2(const int2* __restrict__ bstage,
                                                    const int* __restrict__ bcnt,
                                                    int* __restrict__ off,
                                                    float* __restrict__ dis,
                                                    int* __restrict__ eidx,
                                                    int N, int Etot, int NB) {
    __shared__ int sA[512];
    __shared__ int hist[128];
    __shared__ int lcur[128];
    __shared__ int s_w0;
    __shared__ int leidx[CAP + 128];   // 16.9 KB
    const int t = threadIdx.x;
    const int b = blockIdx.x;
    const int tb = b << NBSH;
    const int ntgt = min(128, N - tb);

    // global edge-prefix over buckets (inclusive Hillis-Steele over 512)
    for (int i = t; i < 512; i += 256) sA[i] = (i < NB) ? bcnt[i] : 0;
    __syncthreads();
    for (int s = 1; s < 512; s <<= 1) {
        int i0 = t, i1 = t + 256;
        int v0 = sA[i0] + ((i0 >= s) ? sA[i0 - s] : 0);
        int v1 = sA[i1] + ((i1 >= s) ? sA[i1 - s] : 0);
        __syncthreads();
        sA[i0] = v0; sA[i1] = v1;
        __syncthreads();
    }
    const int cntb = min(bcnt[b], CAP);
    const int gbase = (sA[b] - bcnt[b]) + tb;   // edges before + self-loops before

    // histogram this bucket's edges per target
    if (t < 128) hist[t] = 0;
    __syncthreads();
    for (int i = t; i < cntb; i += 256)
        atomicAdd(&hist[bstage[b * CAP + i].y - tb], 1);
    __syncthreads();

    // per-target exclusive scan of deg = hist+1 (first 2 waves)
    int v = 0;
    if (t < 128) v = (t < ntgt) ? hist[t] + 1 : 0;
    int sc = v;
#pragma unroll
    for (int d = 1; d < 64; d <<= 1) {
        int y = __shfl_up(sc, d);
        if ((t & 63) >= d) sc += y;
    }
    if (t == 63) s_w0 = sc;
    __syncthreads();
    int ex = sc - v + ((t >= 64 && t < 128) ? s_w0 : 0);
    if (t < ntgt) {
        off[tb + t] = gbase + ex;
        dis[tb + t] = rsqrtf((float)(hist[t] + 1));
        leidx[ex] = tb + t;            // self-loop first
        lcur[t] = ex + 1;
    }
    if (b == 0 && t == 0) off[N] = Etot;
    __syncthreads();

    // scatter edges in LDS, then stream out coalesced
    for (int i = t; i < cntb; i += 256) {
        int2 p = bstage[b * CAP + i];
        int pos = atomicAdd(&lcur[p.y - tb], 1);
        leidx[pos] = p.x;
    }
    __syncthreads();
    const int total = cntb + ntgt;
    for (int i = t; i < total; i += 256)
        eidx[gbase + i] = leidx[i];
}

// ---------------------------------------------- W transpose + fp16 (one-time)
__global__ __launch_bounds__(1024) void transpose_w(const float* __restrict__ W1,
                                                    const float* __restrict__ W2,
                                                    f16* __restrict__ W1t,
                                                    f16* __restrict__ W2t) {
    const float* W = blockIdx.x ? W2 : W1;
    f16* Wt = blockIdx.x ? W2t : W1t;
    __shared__ float Wl[128 * 130];
    const int t = threadIdx.x;
    for (int i = t; i < 16384; i += 1024)
        Wl[(i >> 7) * 130 + (i & 127)] = W[i];
    __syncthreads();
    for (int i = t; i < 16384; i += 1024) {
        int n = i >> 7, k = i & 127;
        Wt[i] = (f16)Wl[k * 130 + n];
    }
}

// ----------------------------------------------------------- MFMA GEMM
// Hh[N,128] (fp16) = A[N,128] (f32 or f16) @ W, using Wt (fp16, [n][k]).
template <typename TA>
__global__ __launch_bounds__(256) void gemm_mfma(const TA* __restrict__ X,
                                                 const f16* __restrict__ Wt,
                                                 f16* __restrict__ Hh, int N) {
    const int w = threadIdx.x >> 6, l = threadIdx.x & 63;
    const int trow = blockIdx.x * 64 + w * 16;
    const int arow = trow + (l & 15);
    const int kg = l >> 4;

    f16x8 a[4];
    const TA* xr = X + (size_t)arow * D;
#pragma unroll
    for (int kt = 0; kt < 4; ++kt) {
        if (arow < N) {
            if constexpr (std::is_same<TA, float>::value) {
                float4 p0 = *(const float4*)&xr[kt * 32 + kg * 8];
                float4 p1 = *(const float4*)&xr[kt * 32 + kg * 8 + 4];
                a[kt][0] = (f16)p0.x; a[kt][1] = (f16)p0.y;
                a[kt][2] = (f16)p0.z; a[kt][3] = (f16)p0.w;
                a[kt][4] = (f16)p1.x; a[kt][5] = (f16)p1.y;
                a[kt][6] = (f16)p1.z; a[kt][7] = (f16)p1.w;
            } else {
                a[kt] = *(const f16x8*)&xr[kt * 32 + kg * 8];
            }
        } else {
#pragma unroll
            for (int j = 0; j < 8; ++j) a[kt][j] = (f16)0.f;
        }
    }

    const int drow = trow + kg * 4;
#pragma unroll
    for (int nt = 0; nt < 8; ++nt) {
        f32x4 acc = {0.f, 0.f, 0.f, 0.f};
        const f16* wrow = Wt + (size_t)(nt * 16 + (l & 15)) * D;
#pragma unroll
        for (int kt = 0; kt < 4; ++kt) {
            f16x8 bfrag = *(const f16x8*)&wrow[kt * 32 + kg * 8];
            acc = __builtin_amdgcn_mfma_f32_16x16x32_f16(a[kt], bfrag, acc, 0, 0, 0);
        }
        const int dcol = nt * 16 + (l & 15);
#pragma unroll
        for (int r = 0; r < 4; ++r) {
            int orow = drow + r;
            if (orow < N) Hh[(size_t)orow * D + dcol] = (f16)acc[r];
        }
    }
}

// ------------------------------------------- SpMM + bias + ReLU, fp16 output
__global__ __launch_bounds__(256) void spmm_relu_f16(const f16* __restrict__ Hh,
                                                     const int* __restrict__ off,
                                                     const int* __restrict__ eidx,
                                                     const float* __restrict__ dis,
                                                     const float* __restrict__ bias,
                                                     f16* __restrict__ Oh, int N) {
    const int c = blockIdx.x * 4 + (threadIdx.x >> 6);
    if (c >= N) return;
    const int lane = threadIdx.x & 63;
    const int d0 = lane * 2;
    const int s = off[c], e = off[c + 1];
    const float dc = dis[c];
    float ax = bias[d0], ay = bias[d0 + 1];
    int k = s;
    for (; k + 8 <= e; k += 8) {
        int r[8];
#pragma unroll
        for (int j = 0; j < 8; ++j) r[j] = eidx[k + j];
        f16x2 h[8];
        float dr[8];
#pragma unroll
        for (int j = 0; j < 8; ++j) {
            h[j] = *(const f16x2*)&Hh[(size_t)r[j] * D + d0];
            dr[j] = dis[r[j]];
        }
#pragma unroll
        for (int j = 0; j < 8; ++j) {
            float w = dr[j] * dc;
            ax += (float)h[j][0] * w;
            ay += (float)h[j][1] * w;
        }
    }
    for (; k < e; ++k) {
        int r = eidx[k];
        f16x2 h = *(const f16x2*)&Hh[(size_t)r * D + d0];
        float w = dis[r] * dc;
        ax += (float)h[0] * w;
        ay += (float)h[1] * w;
    }
    f16x2 o;
    o[0] = (f16)fmaxf(ax, 0.f);
    o[1] = (f16)fmaxf(ay, 0.f);
    *(f16x2*)&Oh[(size_t)c * D + d0] = o;
}

// --------------------------- SpMM + bias + ReLU fused with the 128x3 head
__global__ __launch_bounds__(256) void spmm_head(const f16* __restrict__ Hh,
                                                 const int* __restrict__ off,
                                                 const int* __restrict__ eidx,
                                                 const float* __restrict__ dis,
                                                 const float* __restrict__ bias,
                                                 const float* __restrict__ Wh,
                                                 const float* __restrict__ bh,
                                                 float* __restrict__ out, int N) {
    const int c = blockIdx.x * 4 + (threadIdx.x >> 6);
    if (c >= N) return;
    const int lane = threadIdx.x & 63;
    const int d0 = lane * 2;
    const int s = off[c], e = off[c + 1];
    const float dc = dis[c];
    float ax = bias[d0], ay = bias[d0 + 1];
    int k = s;
    for (; k + 8 <= e; k += 8) {
        int r[8];
#pragma unroll
        for (int j = 0; j < 8; ++j) r[j] = eidx[k + j];
        f16x2 h[8];
        float dr[8];
#pragma unroll
        for (int j = 0; j < 8; ++j) {
            h[j] = *(const f16x2*)&Hh[(size_t)r[j] * D + d0];
            dr[j] = dis[r[j]];
        }
#pragma unroll
        for (int j = 0; j < 8; ++j) {
            float w = dr[j] * dc;
            ax += (float)h[j][0] * w;
            ay += (float)h[j][1] * w;
        }
    }
    for (; k < e; ++k) {
        int r = eidx[k];
        f16x2 h = *(const f16x2*)&Hh[(size_t)r * D + d0];
        float w = dis[r] * dc;
        ax += (float)h[0] * w;
        ay += (float)h[1] * w;
    }
    const float rx = fmaxf(ax, 0.f), ry = fmaxf(ay, 0.f);
    float p0 = rx * Wh[d0 * 3 + 0] + ry * Wh[(d0 + 1) * 3 + 0];
    float p1 = rx * Wh[d0 * 3 + 1] + ry * Wh[(d0 + 1) * 3 + 1];
    float p2 = rx * Wh[d0 * 3 + 2] + ry * Wh[(d0 + 1) * 3 + 2];
#pragma unroll
    for (int sft = 32; sft > 0; sft >>= 1) {
        p0 += __shfl_down(p0, sft);
        p1 += __shfl_down(p1, sft);
        p2 += __shfl_down(p2, sft);
    }
    if (lane == 0) {
        out[(size_t)c * 3 + 0] = p0 + bh[0];
        out[(size_t)c * 3 + 1] = p1 + bh[1];
        out[(size_t)c * 3 + 2] = p2 + bh[2];
    }
}

// ---------------------------------------------------------------------------
extern "C" void kernel_launch(void* const* d_in, const int* in_sizes, int n_in,
                              void* d_out, int out_size, void* d_ws, size_t ws_size,
                              hipStream_t stream) {
    const float* x  = (const float*)d_in[0];
    const int*   ei = (const int*)d_in[1];
    const float* W1 = (const float*)d_in[2];
    const float* b1 = (const float*)d_in[3];
    const float* W2 = (const float*)d_in[4];
    const float* b2 = (const float*)d_in[5];
    const float* Wh = (const float*)d_in[6];
    const float* bh = (const float*)d_in[7];
    float* out = (float*)d_out;

    const int N = in_sizes[0] / D;       // 50000
    const int E = in_sizes[1] / 2;       // 800000
    const int Etot = E + N;
    const int* row = ei;
    const int* col = ei + E;
    const int NB = (N + 127) >> NBSH;    // 391 buckets

    // -------- workspace layout
    char* ws = (char*)d_ws;
    size_t o = 0;
    auto alloc = [&](size_t bytes) -> char* {
        char* p = ws + o;
        o = (o + bytes + 255) & ~(size_t)255;
        return p;
    };
    int*   off    = (int*)  alloc((size_t)(N + 1) * 4);
    float* dis    = (float*)alloc((size_t)N * 4);
    int*   bcur   = (int*)  alloc((size_t)NB * 4);
    int2*  bstage = (int2*) alloc((size_t)NB * CAP * 8);   // 12.8 MB
    int*   eidx   = (int*)  alloc((size_t)Etot * 4);
    f16*   W1t    = (f16*)  alloc((size_t)128 * 128 * 2);
    f16*   W2t    = (f16*)  alloc((size_t)128 * 128 * 2);
    f16*   Hb0    = (f16*)  alloc((size_t)N * D * 2);      // ping
    f16*   Hb1    = (f16*)  alloc((size_t)N * D * 2);      // pong
    (void)ws_size;

    hipMemsetAsync(bcur, 0, (size_t)NB * 4, stream);
    transpose_w<<<2, 1024, 0, stream>>>(W1, W2, W1t, W2t);
    partition_edges<<<(E + CHUNK - 1) / CHUNK, 256, 0, stream>>>(row, col, bcur,
                                                                 bstage, E, NB);
    bucket_fill2<<<NB, 256, 0, stream>>>(bstage, bcur, off, dis, eidx, N, Etot, NB);

    const int gblocks = (N + 63) / 64;
    const int sblocks = (N + 3) / 4;
    gemm_mfma<float><<<gblocks, 256, 0, stream>>>(x, W1t, Hb0, N);
    spmm_relu_f16<<<sblocks, 256, 0, stream>>>(Hb0, off, eidx, dis, b1, Hb1, N);
    gemm_mfma<f16><<<gblocks, 256, 0, stream>>>(Hb1, W2t, Hb0, N);
    spmm_head<<<sblocks, 256, 0, stream>>>(Hb0, off, eidx, dis, b2, Wh, bh, out, N);
}